// Round 7
// baseline (145.481 us; speedup 1.0000x reference)
//
#include <hip/hip_runtime.h>
#include <hip/hip_bf16.h>

#define BATCH 8
#define CIN   64
#define COUT  64
#define HH    128
#define WW    128
#define HW    (HH * WW)
#define ALPHA 8.3f
#define TPX   64
#define YPB   2
#define XW    66
#define YP    (HH + 2)          // 130 padded rows
#define XP    (WW + 2)          // 130 padded cols

// ws layout (in shorts): imgT [8][130][130][64] bf16, then wt [9][64][64] bf16
#define IMGT_SHORTS (BATCH * YP * XP * 64)          // 8,652,800
#define WS_NEED_B   ((IMGT_SHORTS + 9 * 64 * 64) * 2)

typedef __attribute__((ext_vector_type(8))) short short8;   // 8 bf16 = 4 VGPR
typedef __attribute__((ext_vector_type(4))) float f32x4;

// fused prep: image -> padded channel-inner bf16 imgT; weight -> wt [tap][o][c]
__global__ __launch_bounds__(256)
void prep(const float* __restrict__ image, const float* __restrict__ weight,
          __hip_bfloat16* __restrict__ ws) {
    const int bid = blockIdx.x, tid = threadIdx.x;
    if (bid < BATCH * YP) {
        const int b = bid / YP, yp = bid - b * YP;
        __hip_bfloat16* row = ws + (size_t)(b * YP + yp) * XP * 64;
        if (yp == 0 || yp == YP - 1) {
            uint2* p = (uint2*)row;                 // 130*64 shorts = 2080 uint2
            for (int j = tid; j < XP * 64 / 4; j += 256) p[j] = uint2{0u, 0u};
        } else {
            __shared__ __hip_bfloat16 s[WW][66];    // [x][c] padded, 16.9 KB
            const int gy = yp - 1;
            const int c0 = tid >> 7;                // 0..1
            const int gx = tid & 127;
            const float* ip = image + ((size_t)(b * CIN + c0) * HH + gy) * WW + gx;
            #pragma unroll
            for (int cc = 0; cc < 32; ++cc) {
                s[gx][cc * 2 + c0] = __float2bfloat16(ip[0]);
                ip += 2 * HW;
            }
            __syncthreads();
            if (tid < 64) {                         // x' = 0 and 129 zero edges
                const int e = tid >> 5, cp = (tid & 31) * 2;
                ((unsigned*)row)[((e ? (XP - 1) : 0) * 64 + cp) >> 1] = 0u;
            }
            for (int j = tid; j < WW * 64 / 2; j += 256) {
                const int o = j * 2;                // interior x'=1..128
                const int xl = o >> 6, c = o & 63;
                unsigned v = *(const unsigned*)&s[xl][c];
                *(unsigned*)&row[64 + o] = v;
            }
        }
    } else {
        const int i = (bid - BATCH * YP) * 256 + tid;   // 36864 weight elems
        const int c = i & 63, o = (i >> 6) & 63, tap = i >> 12;
        ws[IMGT_SHORTS + i] = __float2bfloat16(weight[(o * 64 + c) * 9 + tap]);
    }
}

// NOTE: plain __launch_bounds__(256). (256,4) capped VGPR at 64 -> wfrag
// spilled -> 200 MB scratch HBM traffic (Round 4). Do not cap.
__global__ __launch_bounds__(256)
void depthconv_main(const short* __restrict__ imgT,   // [b][y'][x'][c] bf16
                    const float* __restrict__ depth,
                    const float* __restrict__ bias,
                    const short* __restrict__ wt,     // [9][o][c] bf16
                    float* __restrict__ out) {
    __shared__ float s_d[4][XW];              // 1056 B
    __shared__ float s_sim[YPB][9][TPX];      // 4608 B

    const int tid = threadIdx.x;
    const int bid = blockIdx.x;
    const int yg = bid & 63;
    const int xt = (bid >> 6) & 1;
    const int b  = bid >> 7;
    const int x0 = xt * TPX;
    const int y0 = yg * YPB;

    const int lane = tid & 63;
    const int wid  = tid >> 6;
    const int l15  = lane & 15;
    const int lq   = lane >> 4;
    const int o_base = wid * 16;

    // A-fragments: 18 b128 loads, L2-resident
    short8 wfrag[9][2];
    #pragma unroll
    for (int tap = 0; tap < 9; ++tap)
        #pragma unroll
        for (int h = 0; h < 2; ++h)
            wfrag[tap][h] = *(const short8*)&wt[(tap * 64 + o_base + l15) * 64 + h * 32 + lq * 8];

    float bias_v[4];
    #pragma unroll
    for (int r = 0; r < 4; ++r) bias_v[r] = bias[o_base + lq * 4 + r];

    // depth rows y0-1..y0+2
    for (int i = tid; i < 4 * XW; i += 256) {
        int rr = i / XW, x = i - rr * XW;
        int gy = y0 - 1 + rr, gx = x0 - 1 + x;
        float v = 0.f;
        if ((unsigned)gy < HH && (unsigned)gx < WW)
            v = depth[(b * HH + gy) * WW + gx];
        s_d[rr][x] = v;
    }
    __syncthreads();
    // sim[yy][tap][p] = exp(-a*|d - d_tap0|), tap0 = (-1,-1)
    for (int i = tid; i < YPB * 9 * TPX; i += 256) {
        int p  = i & 63;
        int t  = i >> 6;
        int yy = t / 9, tap = t - yy * 9;
        int ri = tap / 3, dj = tap - ri * 3;
        float dt = s_d[yy + ri][p + dj];
        float dc = s_d[yy][p];
        s_sim[yy][tap][p] = __expf(-ALPHA * fabsf(dt - dc));
    }
    __syncthreads();

    // compute: B-frags straight from global imgT (channel-inner = frag layout)
    #pragma unroll
    for (int nt = 0; nt < 4; ++nt) {
        const int xb = nt * 16 + l15;
        const short* p = imgT + ((size_t)(b * YP + y0) * XP + (x0 + xb)) * 64 + lq * 8;
        f32x4 a0 = f32x4{0.f, 0.f, 0.f, 0.f};
        f32x4 a1 = f32x4{0.f, 0.f, 0.f, 0.f};

        #pragma unroll
        for (int r = 0; r < 4; ++r) {
            short8 bb[3][2];
            #pragma unroll
            for (int dj = 0; dj < 3; ++dj) {
                bb[dj][0] = *(const short8*)(p + dj * 64);
                bb[dj][1] = *(const short8*)(p + dj * 64 + 32);
            }
            if (r < 3) {                           // feeds y0 (tap row = r)
                #pragma unroll
                for (int dj = 0; dj < 3; ++dj) {
                    const int tap = 3 * r + dj;
                    f32x4 tmp = __builtin_amdgcn_mfma_f32_16x16x32_bf16(
                        wfrag[tap][0], bb[dj][0], (f32x4){0.f, 0.f, 0.f, 0.f}, 0, 0, 0);
                    tmp = __builtin_amdgcn_mfma_f32_16x16x32_bf16(
                        wfrag[tap][1], bb[dj][1], tmp, 0, 0, 0);
                    const float sv = s_sim[0][tap][xb];
                    #pragma unroll
                    for (int e = 0; e < 4; ++e) a0[e] = fmaf(sv, tmp[e], a0[e]);
                }
            }
            if (r >= 1) {                          // feeds y0+1 (tap row = r-1)
                #pragma unroll
                for (int dj = 0; dj < 3; ++dj) {
                    const int tap = 3 * (r - 1) + dj;
                    f32x4 tmp = __builtin_amdgcn_mfma_f32_16x16x32_bf16(
                        wfrag[tap][0], bb[dj][0], (f32x4){0.f, 0.f, 0.f, 0.f}, 0, 0, 0);
                    tmp = __builtin_amdgcn_mfma_f32_16x16x32_bf16(
                        wfrag[tap][1], bb[dj][1], tmp, 0, 0, 0);
                    const float sv = s_sim[1][tap][xb];
                    #pragma unroll
                    for (int e = 0; e < 4; ++e) a1[e] = fmaf(sv, tmp[e], a1[e]);
                }
            }
            p += XP * 64;                          // next padded row
        }

        const int px = x0 + xb;
        #pragma unroll
        for (int rr = 0; rr < 4; ++rr) {
            const int o = o_base + lq * 4 + rr;
            out[((b * COUT + o) * HH + y0) * WW + px]     = a0[rr] + bias_v[rr];
            out[((b * COUT + o) * HH + y0 + 1) * WW + px] = a1[rr] + bias_v[rr];
        }
    }
}

extern "C" void kernel_launch(void* const* d_in, const int* in_sizes, int n_in,
                              void* d_out, int out_size, void* d_ws, size_t ws_size,
                              hipStream_t stream) {
    const float* image  = (const float*)d_in[0];
    const float* depth  = (const float*)d_in[1];
    const float* weight = (const float*)d_in[2];
    const float* bias   = (const float*)d_in[3];
    float* out = (float*)d_out;
    __hip_bfloat16* ws = (__hip_bfloat16*)d_ws;   // needs ~17.4 MB

    // fused prep: 1040 image-row blocks + 144 weight blocks
    prep<<<BATCH * YP + (9 * 64 * 64) / 256, 256, 0, stream>>>(image, weight, ws);

    dim3 grid(BATCH * (HH / YPB) * (WW / TPX));   // 1024
    depthconv_main<<<grid, 256, 0, stream>>>((const short*)ws, depth, bias,
                                             (const short*)ws + IMGT_SHORTS, out);
}

// Round 8
// 113.356 us; speedup vs baseline: 1.2834x; 1.2834x over previous
//
#include <hip/hip_runtime.h>
#include <hip/hip_bf16.h>

#define BATCH 8
#define CIN   64
#define COUT  64
#define HH    128
#define WW    128
#define HW    (HH * WW)
#define ALPHA 8.3f
#define TPX   64
#define XW    66

typedef __attribute__((ext_vector_type(8))) short short8;   // 8 bf16 = 4 VGPR
typedef __attribute__((ext_vector_type(4))) float f32x4;

// index (in shorts) into s_img[6][XW][64], XOR-swizzled in 8-short (16B) slots
__device__ __forceinline__ int img_idx(int r, int x, int c) {
    return (((r * XW + x) << 6) + c) ^ ((x & 7) << 3);
}

// pre-kernel: weight [o][c][k] f32 -> wt [k][o][c] bf16
__global__ __launch_bounds__(256)
void transpose_w(const float* __restrict__ w, __hip_bfloat16* __restrict__ wt) {
    int i = blockIdx.x * 256 + threadIdx.x;
    if (i >= 9 * 64 * 64) return;
    int c = i & 63;
    int o = (i >> 6) & 63;
    int tap = i >> 12;
    wt[i] = __float2bfloat16(w[(o * 64 + c) * 9 + tap]);
}

// NOTE: plain __launch_bounds__(256). (256,4) capped VGPR at 64 -> wfrag
// spilled -> 200 MB scratch HBM traffic (Round 4). Do not cap.
__global__ __launch_bounds__(256)
void depthconv_fused(const float* __restrict__ image,
                     const float* __restrict__ depth,
                     const float* __restrict__ bias,
                     const short* __restrict__ wt,     // [9][64 o][64 c] bf16
                     float* __restrict__ out) {
    __shared__ short s_img[6 * XW * 64];      // 50688 B, rows y0-1..y0+4
    __shared__ float s_d[6][XW];              //  1584 B
    __shared__ float s_sim[4][9][TPX];        //  9216 B

    const int tid = threadIdx.x;
    const int bid = blockIdx.x;
    const int yg = bid & 31;                  // 32 groups of 4 y-rows
    const int xt = (bid >> 5) & 1;
    const int b  = bid >> 6;
    const int x0 = xt * TPX;
    const int y0 = yg * 4;

    const int lane = tid & 63;
    const int wid  = tid >> 6;                // 4 waves, 16 couts each
    const int l15  = lane & 15;
    const int lq   = lane >> 4;
    const int o_base = wid * 16;

    // ---- A-fragments from pre-transposed wt: 18 b128 loads, L2-resident ----
    short8 wfrag[9][2];
    #pragma unroll
    for (int tap = 0; tap < 9; ++tap)
        #pragma unroll
        for (int h = 0; h < 2; ++h)
            wfrag[tap][h] = *(const short8*)&wt[(tap * 64 + o_base + l15) * 64 + h * 32 + lq * 8];

    float bias_v[4];
    #pragma unroll
    for (int r = 0; r < 4; ++r) bias_v[r] = bias[o_base + lq * 4 + r];

    // ---- stage rows 0..3 interior x=1..64: fixed (x,row), loop channels ----
    {
        const int sx  = 1 + (tid & 63);
        const int srr = tid >> 6;                       // 0..3
        const int gy  = y0 - 1 + srr;
        const int gx  = x0 + (tid & 63);                // always in [0,127]
        const bool yok = (unsigned)gy < HH;
        const float* ip = &image[((b * CIN) * HH + (yok ? gy : 0)) * WW + gx];
        const int base = (srr * XW + sx) << 6;
        const int swz  = (sx & 7) << 3;
        #pragma unroll 16
        for (int c2 = 0; c2 < 32; ++c2) {
            float v0 = ip[0], v1 = ip[HW];
            if (!yok) { v0 = 0.f; v1 = 0.f; }
            ip += 2 * HW;
            __hip_bfloat162 pk = __float22bfloat162_rn(float2{v0, v1});
            *(__hip_bfloat162*)&s_img[base + ((2 * c2) ^ swz)] = pk;
        }
    }
    // ---- stage rows 0..3 edge columns x=0,65 ----
    {
        const int e   = tid & 1;
        const int sx  = e ? (XW - 1) : 0;
        const int rr  = (tid >> 1) & 3;
        const int c2  = tid >> 3;                       // 0..31
        const int gy  = y0 - 1 + rr;
        const int gx  = x0 - 1 + sx;
        float v0 = 0.f, v1 = 0.f;
        if ((unsigned)gy < HH && (unsigned)gx < WW) {
            const float* p = &image[((b * CIN + 2 * c2) * HH + gy) * WW + gx];
            v0 = p[0]; v1 = p[HW];
        }
        __hip_bfloat162 pk = __float22bfloat162_rn(float2{v0, v1});
        *(__hip_bfloat162*)&s_img[img_idx(rr, sx, 2 * c2)] = pk;
    }
    // ---- stage 6 depth rows ----
    for (int i = tid; i < 6 * XW; i += 256) {
        int rr = i / XW, x = i - rr * XW;
        int gy = y0 - 1 + rr, gx = x0 - 1 + x;
        float v = 0.f;
        if ((unsigned)gy < HH && (unsigned)gx < WW)
            v = depth[(b * HH + gy) * WW + gx];
        s_d[rr][x] = v;
    }

    // ---- early-issue global loads for rows 4,5 (consumed after pair-0) ----
    float st[32];
    float st_e;
    const int r45  = 4 + (tid >> 7);                    // wave-uniform row 4/5
    const int sx45 = 1 + ((tid >> 1) & 63);
    const int ch0  = (tid & 1) * 32;
    {
        const int gy  = y0 - 1 + r45;
        const bool ok = (unsigned)gy < HH;
        const int gx  = x0 + ((tid >> 1) & 63);
        const float* ip = &image[((size_t)(b * CIN + ch0) * HH + (ok ? gy : 0)) * WW + gx];
        #pragma unroll
        for (int c = 0; c < 32; ++c) {
            float v = ip[0];
            st[c] = ok ? v : 0.f;
            ip += HW;
        }
        const int ee  = (tid >> 6) & 1;
        const int ec  = tid & 63;
        const int gye = y0 - 1 + r45;
        const int gxe = x0 - 1 + (ee ? 65 : 0);
        const bool oke = (unsigned)gye < HH && (unsigned)gxe < WW;
        const float* pe = &image[((size_t)(b * CIN + ec) * HH + (oke ? gye : 0)) * WW + (oke ? gxe : 0)];
        float ve = pe[0];
        st_e = oke ? ve : 0.f;
    }
    __syncthreads();

    // ---- sim for all 4 output rows: exp(-a*|d - d_tap0|), tap0 = (-1,-1) ----
    for (int i = tid; i < 4 * 9 * TPX; i += 256) {
        int p  = i & 63;
        int t  = i >> 6;                                // 0..35
        int yy = t / 9, tap = t - yy * 9;
        int ri = tap / 3, dj = tap - ri * 3;
        float dt = s_d[yy + ri][p + dj];
        float dc = s_d[yy][p];
        s_sim[yy][tap][p] = __expf(-ALPHA * fabsf(dt - dc));
    }
    __syncthreads();

    // ---- compute one y-pair (rows y0+2p, y0+2p+1) from LDS rows 2p..2p+3 ----
    auto compute_pair = [&](const int p) {
        #pragma unroll
        for (int nt = 0; nt < 4; ++nt) {
            const int xb = nt * 16 + l15;
            f32x4 a0 = f32x4{0.f, 0.f, 0.f, 0.f};
            f32x4 a1 = f32x4{0.f, 0.f, 0.f, 0.f};
            #pragma unroll
            for (int r = 0; r < 4; ++r) {
                const int rr = 2 * p + r;
                short8 bb[3][2];
                #pragma unroll
                for (int dj = 0; dj < 3; ++dj) {
                    bb[dj][0] = *(const short8*)&s_img[img_idx(rr, xb + dj, lq * 8)];
                    bb[dj][1] = *(const short8*)&s_img[img_idx(rr, xb + dj, 32 + lq * 8)];
                }
                if (r < 3) {                           // feeds y0+2p
                    #pragma unroll
                    for (int dj = 0; dj < 3; ++dj) {
                        const int tap = 3 * r + dj;
                        f32x4 tmp = __builtin_amdgcn_mfma_f32_16x16x32_bf16(
                            wfrag[tap][0], bb[dj][0], (f32x4){0.f, 0.f, 0.f, 0.f}, 0, 0, 0);
                        tmp = __builtin_amdgcn_mfma_f32_16x16x32_bf16(
                            wfrag[tap][1], bb[dj][1], tmp, 0, 0, 0);
                        const float sv = s_sim[2 * p][tap][xb];
                        #pragma unroll
                        for (int e = 0; e < 4; ++e) a0[e] = fmaf(sv, tmp[e], a0[e]);
                    }
                }
                if (r >= 1) {                          // feeds y0+2p+1
                    #pragma unroll
                    for (int dj = 0; dj < 3; ++dj) {
                        const int tap = 3 * (r - 1) + dj;
                        f32x4 tmp = __builtin_amdgcn_mfma_f32_16x16x32_bf16(
                            wfrag[tap][0], bb[dj][0], (f32x4){0.f, 0.f, 0.f, 0.f}, 0, 0, 0);
                        tmp = __builtin_amdgcn_mfma_f32_16x16x32_bf16(
                            wfrag[tap][1], bb[dj][1], tmp, 0, 0, 0);
                        const float sv = s_sim[2 * p + 1][tap][xb];
                        #pragma unroll
                        for (int e = 0; e < 4; ++e) a1[e] = fmaf(sv, tmp[e], a1[e]);
                    }
                }
            }
            const int px = x0 + xb;
            const int yb = y0 + 2 * p;
            #pragma unroll
            for (int rr = 0; rr < 4; ++rr) {
                const int o = o_base + lq * 4 + rr;
                out[((b * COUT + o) * HH + yb) * WW + px]     = a0[rr] + bias_v[rr];
                out[((b * COUT + o) * HH + yb + 1) * WW + px] = a1[rr] + bias_v[rr];
            }
        }
    };

    compute_pair(0);

    // ---- write rows 4,5 into LDS (they were loaded before the first barrier;
    //      pair-0 only read rows 0..3, so no barrier needed before the write) ----
    {
        const int base = ((r45 * XW + sx45) << 6) + ch0;
        const int swz  = (sx45 & 7) << 3;
        #pragma unroll
        for (int c2 = 0; c2 < 16; ++c2) {
            __hip_bfloat162 pk = __float22bfloat162_rn(float2{st[2 * c2], st[2 * c2 + 1]});
            *(__hip_bfloat162*)&s_img[(base + 2 * c2) ^ swz] = pk;
        }
        const int ee = (tid >> 6) & 1;
        const int ec = tid & 63;
        s_img[img_idx(r45, ee ? (XW - 1) : 0, ec)] =
            __builtin_bit_cast(short, __float2bfloat16(st_e));
    }
    __syncthreads();

    compute_pair(1);
}

extern "C" void kernel_launch(void* const* d_in, const int* in_sizes, int n_in,
                              void* d_out, int out_size, void* d_ws, size_t ws_size,
                              hipStream_t stream) {
    const float* image  = (const float*)d_in[0];
    const float* depth  = (const float*)d_in[1];
    const float* weight = (const float*)d_in[2];
    const float* bias   = (const float*)d_in[3];
    float* out = (float*)d_out;
    __hip_bfloat16* wt = (__hip_bfloat16*)d_ws;       // 9*64*64 bf16 = 73728 B

    transpose_w<<<(9 * 64 * 64 + 255) / 256, 256, 0, stream>>>(weight, wt);

    dim3 grid(BATCH * 2 * 32);                        // 512 blocks, 4 y-rows each
    depthconv_fused<<<grid, 256, 0, stream>>>(image, depth, bias,
                                              (const short*)wt, out);
}

// Round 9
// 110.369 us; speedup vs baseline: 1.3181x; 1.0271x over previous
//
#include <hip/hip_runtime.h>
#include <hip/hip_bf16.h>

#define BATCH 8
#define CIN   64
#define COUT  64
#define HH    128
#define WW    128
#define HW    (HH * WW)
#define ALPHA 8.3f
#define TPX   64
#define XW    66

typedef __attribute__((ext_vector_type(8))) short short8;   // 8 bf16 = 4 VGPR
typedef __attribute__((ext_vector_type(4))) float f32x4;

// index (in shorts) into s_img[6][XW][64], XOR-swizzled in 8-short (16B) slots
__device__ __forceinline__ int img_idx(int r, int x, int c) {
    return (((r * XW + x) << 6) + c) ^ ((x & 7) << 3);
}

// pre-kernel: weight [o][c][k] f32 -> wt [k][o][c] bf16
__global__ __launch_bounds__(256)
void transpose_w(const float* __restrict__ w, __hip_bfloat16* __restrict__ wt) {
    int i = blockIdx.x * 256 + threadIdx.x;
    if (i >= 9 * 64 * 64) return;
    int c = i & 63;
    int o = (i >> 6) & 63;
    int tap = i >> 12;
    wt[i] = __float2bfloat16(w[(o * 64 + c) * 9 + tap]);
}

// 512 threads = 8 waves: waves 0-3 compute y-pair 0, waves 4-7 pair 1.
// LDS 61.5 KB -> 2 blocks/CU = 16 waves/CU (needs VGPR <= 128; est ~117).
// NOTE: plain __launch_bounds__. A min-occupancy cap (256,4) in Round 4
// forced VGPR=64 -> wfrag spill -> 200 MB scratch traffic. Do not cap.
__global__ __launch_bounds__(512)
void depthconv_fused(const float* __restrict__ image,
                     const float* __restrict__ depth,
                     const float* __restrict__ bias,
                     const short* __restrict__ wt,     // [9][64 o][64 c] bf16
                     float* __restrict__ out) {
    __shared__ short s_img[6 * XW * 64];      // 50688 B, rows y0-1..y0+4
    __shared__ float s_d[6][XW];              //  1584 B
    __shared__ float s_sim[4][9][TPX];        //  9216 B  (total 61488)

    const int tid = threadIdx.x;
    const int bid = blockIdx.x;
    const int yg = bid & 31;                  // 32 groups of 4 y-rows
    const int xt = (bid >> 5) & 1;
    const int b  = bid >> 6;
    const int x0 = xt * TPX;
    const int y0 = yg * 4;

    const int lane = tid & 63;
    const int wid  = tid >> 6;                // 0..7
    const int l15  = lane & 15;
    const int lq   = lane >> 4;
    const int og   = wid & 3;                 // o-group
    const int pr   = wid >> 2;                // y-pair 0/1
    const int o_base = og * 16;

    // ---- staging: wave = row slot ----
    if (wid < 6) {
        // interior x=1..64 of window row `wid`: fixed (x,row), loop channels
        const int sx  = 1 + lane;
        const int gy  = y0 - 1 + wid;
        const bool yok = (unsigned)gy < HH;
        const int gx  = x0 + lane;                      // in [0,127]
        const float* ip = &image[((b * CIN) * HH + (yok ? gy : 0)) * WW + gx];
        const int base = (wid * XW + sx) << 6;
        const int swz  = (sx & 7) << 3;
        #pragma unroll 16
        for (int c2 = 0; c2 < 32; ++c2) {
            float v0 = ip[0], v1 = ip[HW];
            if (!yok) { v0 = 0.f; v1 = 0.f; }
            ip += 2 * HW;
            __hip_bfloat162 pk = __float22bfloat162_rn(float2{v0, v1});
            *(__hip_bfloat162*)&s_img[base + ((2 * c2) ^ swz)] = pk;
        }
    } else if (wid == 6) {
        // edge columns x=0,65 for all 6 rows: threads 0..11 each do one (row,edge)
        if (lane < 12) {
            const int rr = lane >> 1, e = lane & 1;
            const int sx = e ? (XW - 1) : 0;
            const int gy = y0 - 1 + rr;
            const int gx = x0 - 1 + sx;
            const bool ok = (unsigned)gy < HH && (unsigned)gx < WW;
            const float* p = &image[((b * CIN) * HH + (ok ? gy : 0)) * WW + (ok ? gx : 0)];
            #pragma unroll 8
            for (int c2 = 0; c2 < 32; ++c2) {
                float v0 = p[0], v1 = p[HW];
                if (!ok) { v0 = 0.f; v1 = 0.f; }
                p += 2 * HW;
                __hip_bfloat162 pk = __float22bfloat162_rn(float2{v0, v1});
                *(__hip_bfloat162*)&s_img[img_idx(rr, sx, 2 * c2)] = pk;
            }
        }
    } else {
        // depth rows y0-1..y0+4
        for (int i = lane; i < 6 * XW; i += 64) {
            int rr = i / XW, x = i - rr * XW;
            int gy = y0 - 1 + rr, gx = x0 - 1 + x;
            float v = 0.f;
            if ((unsigned)gy < HH && (unsigned)gx < WW)
                v = depth[(b * HH + gy) * WW + gx];
            s_d[rr][x] = v;
        }
    }
    __syncthreads();

    // ---- sim for 4 output rows: exp(-a*|d - d_tap0|), tap0 = (-1,-1) ----
    for (int i = tid; i < 4 * 9 * TPX; i += 512) {
        int p  = i & 63;
        int t  = i >> 6;                                // 0..35
        int yy = t / 9, tap = t - yy * 9;
        int ri = tap / 3, dj = tap - ri * 3;
        float dt = s_d[yy + ri][p + dj];
        float dc = s_d[yy][p];
        s_sim[yy][tap][p] = __expf(-ALPHA * fabsf(dt - dc));
    }

    // ---- A-fragments (loaded post-staging so staging regs are dead) ----
    short8 wfrag[9][2];
    #pragma unroll
    for (int tap = 0; tap < 9; ++tap)
        #pragma unroll
        for (int h = 0; h < 2; ++h)
            wfrag[tap][h] = *(const short8*)&wt[(tap * 64 + o_base + l15) * 64 + h * 32 + lq * 8];

    float bias_v[4];
    #pragma unroll
    for (int r = 0; r < 4; ++r) bias_v[r] = bias[o_base + lq * 4 + r];

    __syncthreads();

    // ---- compute this wave's y-pair (rows y0+2pr, y0+2pr+1), window rows 2pr..2pr+3 ----
    #pragma unroll
    for (int nt = 0; nt < 4; ++nt) {
        const int xb = nt * 16 + l15;
        f32x4 a0 = f32x4{0.f, 0.f, 0.f, 0.f};
        f32x4 a1 = f32x4{0.f, 0.f, 0.f, 0.f};
        #pragma unroll
        for (int r = 0; r < 4; ++r) {
            const int rr = 2 * pr + r;
            short8 bb[3][2];
            #pragma unroll
            for (int dj = 0; dj < 3; ++dj) {
                bb[dj][0] = *(const short8*)&s_img[img_idx(rr, xb + dj, lq * 8)];
                bb[dj][1] = *(const short8*)&s_img[img_idx(rr, xb + dj, 32 + lq * 8)];
            }
            if (r < 3) {                           // feeds row y0+2pr
                #pragma unroll
                for (int dj = 0; dj < 3; ++dj) {
                    const int tap = 3 * r + dj;
                    f32x4 tmp = __builtin_amdgcn_mfma_f32_16x16x32_bf16(
                        wfrag[tap][0], bb[dj][0], (f32x4){0.f, 0.f, 0.f, 0.f}, 0, 0, 0);
                    tmp = __builtin_amdgcn_mfma_f32_16x16x32_bf16(
                        wfrag[tap][1], bb[dj][1], tmp, 0, 0, 0);
                    const float sv = s_sim[2 * pr][tap][xb];
                    #pragma unroll
                    for (int e = 0; e < 4; ++e) a0[e] = fmaf(sv, tmp[e], a0[e]);
                }
            }
            if (r >= 1) {                          // feeds row y0+2pr+1
                #pragma unroll
                for (int dj = 0; dj < 3; ++dj) {
                    const int tap = 3 * (r - 1) + dj;
                    f32x4 tmp = __builtin_amdgcn_mfma_f32_16x16x32_bf16(
                        wfrag[tap][0], bb[dj][0], (f32x4){0.f, 0.f, 0.f, 0.f}, 0, 0, 0);
                    tmp = __builtin_amdgcn_mfma_f32_16x16x32_bf16(
                        wfrag[tap][1], bb[dj][1], tmp, 0, 0, 0);
                    const float sv = s_sim[2 * pr + 1][tap][xb];
                    #pragma unroll
                    for (int e = 0; e < 4; ++e) a1[e] = fmaf(sv, tmp[e], a1[e]);
                }
            }
        }
        const int px = x0 + xb;
        const int yb = y0 + 2 * pr;
        #pragma unroll
        for (int rr = 0; rr < 4; ++rr) {
            const int o = o_base + lq * 4 + rr;
            out[((b * COUT + o) * HH + yb) * WW + px]     = a0[rr] + bias_v[rr];
            out[((b * COUT + o) * HH + yb + 1) * WW + px] = a1[rr] + bias_v[rr];
        }
    }
}

extern "C" void kernel_launch(void* const* d_in, const int* in_sizes, int n_in,
                              void* d_out, int out_size, void* d_ws, size_t ws_size,
                              hipStream_t stream) {
    const float* image  = (const float*)d_in[0];
    const float* depth  = (const float*)d_in[1];
    const float* weight = (const float*)d_in[2];
    const float* bias   = (const float*)d_in[3];
    float* out = (float*)d_out;
    __hip_bfloat16* wt = (__hip_bfloat16*)d_ws;       // 9*64*64 bf16 = 73728 B

    transpose_w<<<(9 * 64 * 64 + 255) / 256, 256, 0, stream>>>(weight, wt);

    dim3 grid(BATCH * 2 * 32);                        // 512 blocks, 4 y-rows each
    depthconv_fused<<<grid, 512, 0, stream>>>(image, depth, bias,
                                              (const short*)wt, out);
}